// Round 4
// baseline (287.175 us; speedup 1.0000x reference)
//
#include <hip/hip_runtime.h>
#include <math.h>

#define BB 4
#define NN 16384
#define CC 384
#define NE 128
#define KK 64
#define EQCAP 256

typedef unsigned short ushort_t;
typedef __attribute__((ext_vector_type(8))) short bf16x8;
typedef __attribute__((ext_vector_type(4))) float f32x4;
#define MFMA(a, b, c) __builtin_amdgcn_mfma_f32_16x16x32_bf16(a, b, c, 0, 0, 0)

// Monotone map: larger float -> larger u32
__device__ inline unsigned fkey(float f) {
    unsigned b = __float_as_uint(f);
    return (b & 0x80000000u) ? ~b : (b | 0x80000000u);
}
__device__ inline ushort_t bf16rne(float f) {
    unsigned u = __float_as_uint(f);
    unsigned r = u + 0x7FFFu + ((u >> 16) & 1u);
    return (ushort_t)(r >> 16);
}
__device__ inline float bf16tof(ushort_t h) {
    return __uint_as_float(((unsigned)h) << 16);
}
// Cheap near-RNE hi/lo split for a pair of floats (unbiased residual ~2^-17)
__device__ inline void cvt2(float fa, float fb, unsigned& hp, unsigned& lp) {
    unsigned ua = __float_as_uint(fa), ub = __float_as_uint(fb);
    unsigned ra = ua + 0x8000u, rb = ub + 0x8000u;
    hp = (ra >> 16) | (rb & 0xFFFF0000u);
    float ha = __uint_as_float(ra & 0xFFFF0000u);
    float hb = __uint_as_float(rb & 0xFFFF0000u);
    float la = fa - ha, lb = fb - hb;           // exact (Sterbenz)
    unsigned lra = __float_as_uint(la) + 0x8000u;
    unsigned lrb = __float_as_uint(lb) + 0x8000u;
    lp = (lra >> 16) | (lrb & 0xFFFF0000u);
}
// width-16 global -> LDS direct (lane i lands at lds_base + 16*i)
__device__ inline void gload16(const void* g, void* l) {
    __builtin_amdgcn_global_load_lds(
        (const __attribute__((address_space(1))) void*)g,
        (__attribute__((address_space(3))) void*)l, 16, 0, 0);
}

// Parallel bin select over 256-bin LDS histogram (1024 threads).
__device__ inline void bin_select(unsigned* hist, int t, int* wsum,
                                  int* sh_bin, int* sh_r, int r) {
    int lane = t & 63, wid = t >> 6;
    int c = (t < 256) ? (int)hist[t] : 0;
    int x = c;
#pragma unroll
    for (int off = 1; off < 64; off <<= 1) {
        int v = __shfl_down(x, off, 64);
        if (lane + off < 64) x += v;
    }
    if (lane == 0 && wid < 4) wsum[wid] = x;
    __syncthreads();
    if (t < 256) {
        int add = 0;
        for (int w2 = wid + 1; w2 < 4; ++w2) add += wsum[w2];
        int S_incl = x + add;
        int S_excl = S_incl - c;
        if (S_excl < r && S_incl >= r) { *sh_bin = t; *sh_r = r - S_excl; }
    }
    __syncthreads();
}

// ---------------- K1: per-row sumsq + class-token dot -> u32 ranking key ----------------
__global__ __launch_bounds__(256) void k_scores(const float* __restrict__ nf,
                                                const float* __restrict__ ct,
                                                unsigned* __restrict__ keys,
                                                float* __restrict__ invn) {
    int wave = threadIdx.x >> 6;
    int lane = threadIdx.x & 63;
    int row  = blockIdx.x * 4 + wave;
    const float* x = nf + (size_t)row * CC;
    float4 a  = ((const float4*)x)[lane];
    float2 c2 = ((const float2*)(x + 256))[lane];
    float4 ta = ((const float4*)ct)[lane];
    float2 tc = ((const float2*)(ct + 256))[lane];
    float ss = a.x*a.x + a.y*a.y + a.z*a.z + a.w*a.w + c2.x*c2.x + c2.y*c2.y;
    float dt = ta.x*a.x + ta.y*a.y + ta.z*a.z + ta.w*a.w + tc.x*c2.x + tc.y*c2.y;
#pragma unroll
    for (int off = 32; off; off >>= 1) {
        ss += __shfl_xor(ss, off, 64);
        dt += __shfl_xor(dt, off, 64);
    }
    if (lane == 0) {
        float inv = 1.0f / fmaxf(sqrtf(ss), 1e-12f);
        invn[row] = inv;
        keys[row] = fkey(dt * inv);
    }
}

// ---------------- K2: top-128 per batch (radix select) + fused center gather/split ----------------
__global__ __launch_bounds__(1024) void k_top128(const unsigned* __restrict__ keys,
                                                 const float* __restrict__ nf,
                                                 const float* __restrict__ invn,
                                                 ushort_t* __restrict__ Ahi,
                                                 ushort_t* __restrict__ Alo,
                                                 float* __restrict__ meta) {
    __shared__ unsigned hist[256];
    __shared__ int wsum[4];
    __shared__ int sh_bin, sh_r;
    __shared__ unsigned cu[NE];
    __shared__ int cil[NE];
    __shared__ int eqi[EQCAP];
    __shared__ int cnt_gt, cnt_eq;
    __shared__ int ocid[NE];
    int b = blockIdx.x;
    int t = threadIdx.x;
    const uint4* rowv = (const uint4*)(keys + b * NN);
    if (t == 0) { cnt_gt = 0; cnt_eq = 0; }
    unsigned prefix = 0;
    int r = NE;
#pragma unroll
    for (int pass = 0; pass < 4; ++pass) {
        int shift = 24 - 8 * pass;
        unsigned hm = (pass == 0) ? 0u : (0xFFFFFFFFu << (shift + 8));
        if (t < 256) hist[t] = 0;
        __syncthreads();
#pragma unroll
        for (int i = 0; i < 4; ++i) {
            uint4 u = rowv[t + 1024 * i];
            if ((u.x & hm) == (prefix & hm)) atomicAdd(&hist[(u.x >> shift) & 255], 1u);
            if ((u.y & hm) == (prefix & hm)) atomicAdd(&hist[(u.y >> shift) & 255], 1u);
            if ((u.z & hm) == (prefix & hm)) atomicAdd(&hist[(u.z >> shift) & 255], 1u);
            if ((u.w & hm) == (prefix & hm)) atomicAdd(&hist[(u.w >> shift) & 255], 1u);
        }
        __syncthreads();
        bin_select(hist, t, wsum, &sh_bin, &sh_r, r);
        prefix |= ((unsigned)sh_bin) << shift;
        r = sh_r;
        __syncthreads();
    }
    unsigned T = prefix;
#pragma unroll
    for (int i = 0; i < 4; ++i) {
        uint4 u = rowv[t + 1024 * i];
        int nb = 4 * (t + 1024 * i);
        unsigned vv[4] = {u.x, u.y, u.z, u.w};
#pragma unroll
        for (int cmp = 0; cmp < 4; ++cmp) {
            if (vv[cmp] > T) {
                int p = atomicAdd(&cnt_gt, 1);
                cu[p] = vv[cmp]; cil[p] = nb + cmp;
            } else if (vv[cmp] == T) {
                int p = atomicAdd(&cnt_eq, 1);
                if (p < EQCAP) eqi[p] = nb + cmp;
            }
        }
    }
    __syncthreads();
    int ne = cnt_eq < EQCAP ? cnt_eq : EQCAP;
    if (t < ne) {
        int mine = eqi[t], rk = 0;
        for (int j = 0; j < ne; ++j) rk += (eqi[j] < mine);
        if (rk < r) { int p = cnt_gt + rk; cu[p] = T; cil[p] = mine; }
    }
    __syncthreads();
    if (t < NE) {
        unsigned mu = cu[t]; int mi = cil[t], rk = 0;
#pragma unroll 4
        for (int j = 0; j < NE; ++j) {
            unsigned ou = cu[j]; int oi = cil[j];
            rk += (ou > mu) || (ou == mu && oi < mi);
        }
        ocid[rk] = mi;
    }
    __syncthreads();
    // ---- fused: gather centers, l2-normalize, exact-RNE bf16 hi/lo split ----
    {
        int e = t >> 3, part = t & 7;       // 128 edges x 8 threads
        int ci = ocid[e];
        float inv = invn[b * NN + ci];
        const float4* src = (const float4*)(nf + ((size_t)b * NN + ci) * CC) + part * 12;
        ushort_t* dh = Ahi + ((size_t)b * NE + e) * CC + part * 48;
        ushort_t* dl = Alo + ((size_t)b * NE + e) * CC + part * 48;
#pragma unroll
        for (int i = 0; i < 12; ++i) {
            float4 f = src[i];
            f.x *= inv; f.y *= inv; f.z *= inv; f.w *= inv;
            ushort4 h, l;
            h.x = bf16rne(f.x); l.x = bf16rne(f.x - bf16tof(h.x));
            h.y = bf16rne(f.y); l.y = bf16rne(f.y - bf16tof(h.y));
            h.z = bf16rne(f.z); l.z = bf16rne(f.z - bf16tof(h.z));
            h.w = bf16rne(f.w); l.w = bf16rne(f.w - bf16tof(h.w));
            ((ushort4*)dh)[i] = h;
            ((ushort4*)dl)[i] = l;
        }
    }
    if (t < NE) {
        int ci = ocid[t];
        float zc = (float)(ci >> 10) * 2.0f;
        float yc = (float)((ci >> 5) & 31);
        float xc = (float)(ci & 31);
        float mz = fmaxf(zc * zc, (30.f - zc) * (30.f - zc));
        float my = fmaxf(yc * yc, (31.f - yc) * (31.f - yc));
        float mx = fmaxf(xc * xc, (31.f - xc) * (31.f - xc));
        float md = sqrtf(mz + my + mx);
        int be = b * NE + t;
        meta[be * 4 + 0] = zc;
        meta[be * 4 + 1] = yc;
        meta[be * 4 + 2] = xc;
        meta[be * 4 + 3] = 1.0f / (md + 1e-8f);
    }
}

// ---------------- K3: bf16-split MFMA GEMM, 128 edges x 64 nodes/block ----------------
// acc = Ahi*Bhi + Ahi*Blo + Alo*Bhi  (fp32 accum). A via global_load_lds (pre-split),
// B converted in-flight with cheap-RNE split. Grid 1024 blocks = 4 blocks/CU.
__global__ __launch_bounds__(256, 4) void k_gemm(const float* __restrict__ nf,
                                                 const ushort_t* __restrict__ Ahi,
                                                 const ushort_t* __restrict__ Alo,
                                                 const float* __restrict__ invn,
                                                 const float* __restrict__ meta,
                                                 const float* __restrict__ temp,
                                                 unsigned* __restrict__ outk) {
    __shared__ ushort_t Ah[4096], Al[4096];    // [ec 8][k8 4][e16 16][8]
    __shared__ ushort_t Bhs[2048], Bls[2048];  // [k8 4][n 64][8]
    __shared__ float ms[NE * 4];
    __shared__ float invs_s[64];
    int b  = blockIdx.y;
    int n0 = blockIdx.x * 64;
    int t  = threadIdx.x;
    int w = t >> 6, lane = t & 63, quad = lane >> 4, mrow = lane & 15;
    int m0 = (w & 1) * 64, nw0 = (w >> 1) * 32;
    for (int i = t; i < NE * 4; i += 256) ms[i] = meta[b * NE * 4 + i];
    if (t < 64) invs_s[t] = invn[b * NN + n0 + t];
    f32x4 acc[4][2];
#pragma unroll
    for (int i = 0; i < 4; ++i)
#pragma unroll
        for (int j = 0; j < 2; ++j) acc[i][j] = (f32x4)0.f;
    const ushort_t* Abh = Ahi + (size_t)b * NE * CC;
    const ushort_t* Abl = Alo + (size_t)b * NE * CC;
    const float* Bb = nf + ((size_t)b * NN + n0) * CC;
    int bn = t >> 2, bk8 = t & 3;
    const float* bsrc = Bb + (size_t)bn * CC + bk8 * 8;
    ushort_t* bh_dst = &Bhs[(bk8 * 64 + bn) * 8];
    ushort_t* bl_dst = &Bls[(bk8 * 64 + bn) * 8];
    // A-load lane addressing: k8 = quad, e16 = mrow, wave w covers ec = {w, w+4}
    const ushort_t* agh0 = Abh + (size_t)(w * 16 + mrow) * CC + quad * 8;
    const ushort_t* agh1 = Abh + (size_t)((w + 4) * 16 + mrow) * CC + quad * 8;
    const ushort_t* agl0 = Abl + (size_t)(w * 16 + mrow) * CC + quad * 8;
    const ushort_t* agl1 = Abl + (size_t)((w + 4) * 16 + mrow) * CC + quad * 8;
    for (int kt = 0; kt < CC; kt += 32) {
        __syncthreads();
        gload16(agh0 + kt, &Ah[w * 512]);
        gload16(agh1 + kt, &Ah[(w + 4) * 512]);
        gload16(agl0 + kt, &Al[w * 512]);
        gload16(agl1 + kt, &Al[(w + 4) * 512]);
        {
            const float4* bs = (const float4*)(bsrc + kt);
            float4 f0 = bs[0];
            float4 f1 = bs[1];
            uint4 ph, pl;
            cvt2(f0.x, f0.y, ph.x, pl.x);
            cvt2(f0.z, f0.w, ph.y, pl.y);
            cvt2(f1.x, f1.y, ph.z, pl.z);
            cvt2(f1.z, f1.w, ph.w, pl.w);
            *(uint4*)bh_dst = ph;
            *(uint4*)bl_dst = pl;
        }
        __syncthreads();
        bf16x8 afh[4], afl[4], bfh[2], bfl[2];
#pragma unroll
        for (int i = 0; i < 4; ++i) {
            int m = m0 + i * 16 + mrow;
            int off = (m >> 4) * 512 + quad * 128 + (m & 15) * 8;
            afh[i] = *(const bf16x8*)&Ah[off];
            afl[i] = *(const bf16x8*)&Al[off];
        }
#pragma unroll
        for (int j = 0; j < 2; ++j) {
            int n = nw0 + j * 16 + mrow;
            bfh[j] = *(const bf16x8*)&Bhs[(quad * 64 + n) * 8];
            bfl[j] = *(const bf16x8*)&Bls[(quad * 64 + n) * 8];
        }
#pragma unroll
        for (int i = 0; i < 4; ++i)
#pragma unroll
            for (int j = 0; j < 2; ++j) {
                acc[i][j] = MFMA(afh[i], bfh[j], acc[i][j]);
                acc[i][j] = MFMA(afh[i], bfl[j], acc[i][j]);
                acc[i][j] = MFMA(afl[i], bfh[j], acc[i][j]);
            }
    }
    float scale = 0.9f / temp[0];
#pragma unroll
    for (int j = 0; j < 2; ++j) {
        int nloc = nw0 + j * 16 + mrow;
        int n = n0 + nloc;
        float invnn = invs_s[nloc];
        float zf = (float)(n >> 10) * 2.0f;
        float yf = (float)((n >> 5) & 31);
        float xf = (float)(n & 31);
#pragma unroll
        for (int i = 0; i < 4; ++i) {
#pragma unroll
            for (int r = 0; r < 4; ++r) {
                int e = m0 + i * 16 + quad * 4 + r;
                float zc = ms[e * 4 + 0], yc = ms[e * 4 + 1], xc = ms[e * 4 + 2], ivd = ms[e * 4 + 3];
                float dz = zf - zc, dy = yf - yc, dx = xf - xc;
                float dist = sqrtf(dz * dz + dy * dy + dx * dx);
                float v = scale * invnn * acc[i][j][r] + 0.1f * (1.0f - dist * ivd);
                outk[((size_t)(b * NE + e)) * NN + n] = fkey(v);
            }
        }
    }
}

// ---------------- K4: top-64 per hyperedge via radix select (set only) ----------------
__global__ __launch_bounds__(1024) void k_top64(const unsigned* __restrict__ comb,
                                                int* __restrict__ sel) {
    __shared__ unsigned hist[256];
    __shared__ int wsum[4];
    __shared__ int sh_bin, sh_r;
    __shared__ int eqi[EQCAP];
    __shared__ int cnt_gt, cnt_eq;
    int be = blockIdx.x;
    int t  = threadIdx.x;
    const uint4* rowv = (const uint4*)(comb + (size_t)be * NN);
    if (t == 0) { cnt_gt = 0; cnt_eq = 0; }
    unsigned prefix = 0;
    int r = KK;
#pragma unroll
    for (int pass = 0; pass < 4; ++pass) {
        int shift = 24 - 8 * pass;
        unsigned hm = (pass == 0) ? 0u : (0xFFFFFFFFu << (shift + 8));
        if (t < 256) hist[t] = 0;
        __syncthreads();
#pragma unroll
        for (int i = 0; i < 4; ++i) {
            uint4 u = rowv[t + 1024 * i];
            if ((u.x & hm) == (prefix & hm)) atomicAdd(&hist[(u.x >> shift) & 255], 1u);
            if ((u.y & hm) == (prefix & hm)) atomicAdd(&hist[(u.y >> shift) & 255], 1u);
            if ((u.z & hm) == (prefix & hm)) atomicAdd(&hist[(u.z >> shift) & 255], 1u);
            if ((u.w & hm) == (prefix & hm)) atomicAdd(&hist[(u.w >> shift) & 255], 1u);
        }
        __syncthreads();
        bin_select(hist, t, wsum, &sh_bin, &sh_r, r);
        prefix |= ((unsigned)sh_bin) << shift;
        r = sh_r;
        __syncthreads();
    }
    unsigned T = prefix;
#pragma unroll
    for (int i = 0; i < 4; ++i) {
        uint4 u = rowv[t + 1024 * i];
        int nb = 4 * (t + 1024 * i);
        unsigned vv[4] = {u.x, u.y, u.z, u.w};
#pragma unroll
        for (int cmp = 0; cmp < 4; ++cmp) {
            if (vv[cmp] > T) {
                int p = atomicAdd(&cnt_gt, 1);
                sel[be * KK + p] = nb + cmp;
            } else if (vv[cmp] == T) {
                int p = atomicAdd(&cnt_eq, 1);
                if (p < EQCAP) eqi[p] = nb + cmp;
            }
        }
    }
    __syncthreads();
    int ne = cnt_eq < EQCAP ? cnt_eq : EQCAP;
    if (t < ne) {
        int mine = eqi[t], rk = 0;
        for (int j = 0; j < ne; ++j) rk += (eqi[j] < mine);
        if (rk < r) sel[be * KK + cnt_gt + rk] = mine;
    }
}

// ---------------- K5: scatter ones into H (B, N, Ne) ----------------
__global__ __launch_bounds__(256) void k_scatter(const int* __restrict__ sel,
                                                 float* __restrict__ H) {
    int gid = blockIdx.x * 256 + threadIdx.x;
    int b = gid >> 13;
    int e = (gid >> 6) & 127;
    int n = sel[gid];
    H[((size_t)b * NN + n) * NE + e] = 1.0f;
}

extern "C" void kernel_launch(void* const* d_in, const int* in_sizes, int n_in,
                              void* d_out, int out_size, void* d_ws, size_t ws_size,
                              hipStream_t stream) {
    const float* nf   = (const float*)d_in[0];
    const float* ct   = (const float*)d_in[1];
    const float* temp = (const float*)d_in[2];
    float* out = (float*)d_out;                  // (B,N,Ne) f32 — also (B,Ne,N) u32-key scratch

    unsigned* keys = (unsigned*)d_ws;                      // B*N u32
    float* invn    = (float*)(keys + BB * NN);             // B*N f32
    float* meta    = invn + BB * NN;                       // B*NE*4 f32
    ushort_t* Ahi  = (ushort_t*)(meta + BB * NE * 4);      // B*NE*C bf16
    ushort_t* Alo  = Ahi + (size_t)BB * NE * CC;           // B*NE*C bf16
    int* sel       = (int*)(Alo + (size_t)BB * NE * CC);   // B*NE*KK

    k_scores <<<BB * NN / 4, 256, 0, stream>>>(nf, ct, keys, invn);
    k_top128 <<<BB, 1024, 0, stream>>>(keys, nf, invn, Ahi, Alo, meta);
    k_gemm   <<<dim3(NN / 64, BB), 256, 0, stream>>>(nf, Ahi, Alo, invn, meta, temp, (unsigned*)out);
    k_top64  <<<BB * NE, 1024, 0, stream>>>((const unsigned*)out, sel);
    hipMemsetAsync(d_out, 0, (size_t)BB * NN * NE * sizeof(float), stream);
    k_scatter<<<BB * NE * KK / 256, 256, 0, stream>>>(sel, out);
}

// Round 5
// 254.428 us; speedup vs baseline: 1.1287x; 1.1287x over previous
//
#include <hip/hip_runtime.h>
#include <math.h>

#define BB 4
#define NN 16384
#define CC 384
#define NE 128
#define KK 64
#define CAP 1024

typedef unsigned short ushort_t;
typedef __attribute__((ext_vector_type(8))) short bf16x8;
typedef __attribute__((ext_vector_type(4))) float f32x4;
#define MFMA(a, b, c) __builtin_amdgcn_mfma_f32_16x16x32_bf16(a, b, c, 0, 0, 0)

// Monotone map: larger float -> larger u32
__device__ inline unsigned fkey(float f) {
    unsigned b = __float_as_uint(f);
    return (b & 0x80000000u) ? ~b : (b | 0x80000000u);
}
__device__ inline ushort_t bf16rne(float f) {
    unsigned u = __float_as_uint(f);
    unsigned r = u + 0x7FFFu + ((u >> 16) & 1u);
    return (ushort_t)(r >> 16);
}
__device__ inline float bf16tof(ushort_t h) {
    return __uint_as_float(((unsigned)h) << 16);
}
// Cheap near-RNE hi/lo split for a pair of floats (unbiased residual ~2^-17)
__device__ inline void cvt2(float fa, float fb, unsigned& hp, unsigned& lp) {
    unsigned ua = __float_as_uint(fa), ub = __float_as_uint(fb);
    unsigned ra = ua + 0x8000u, rb = ub + 0x8000u;
    hp = (ra >> 16) | (rb & 0xFFFF0000u);
    float ha = __uint_as_float(ra & 0xFFFF0000u);
    float hb = __uint_as_float(rb & 0xFFFF0000u);
    float la = fa - ha, lb = fb - hb;           // exact (Sterbenz)
    unsigned lra = __float_as_uint(la) + 0x8000u;
    unsigned lrb = __float_as_uint(lb) + 0x8000u;
    lp = (lra >> 16) | (lrb & 0xFFFF0000u);
}

// Parallel bin select over 4096-bin LDS histogram (1024 threads, 16 waves).
// Finds bin s.t. (#elems in bins > bin) < r <= (#elems in bins >= bin).
__device__ inline void bin_select4k(const unsigned* hist, int t, int* wsum,
                                    int* sh_bin, int* sh_r, int r) {
    int base = t * 4;
    int c0 = hist[base], c1 = hist[base + 1], c2 = hist[base + 2], c3 = hist[base + 3];
    int csum = c0 + c1 + c2 + c3;
    int lane = t & 63, wid = t >> 6;
    int x = csum;
#pragma unroll
    for (int off = 1; off < 64; off <<= 1) {
        int v = __shfl_down(x, off, 64);
        if (lane + off < 64) x += v;     // inclusive suffix within wave
    }
    if (lane == 0) wsum[wid] = x;
    __syncthreads();
    int after = 0;
    for (int w2 = wid + 1; w2 < 16; ++w2) after += wsum[w2];
    int S = x - csum + after;            // elems in bins strictly above base+3
    if (S < r && S + c3 >= r) { *sh_bin = base + 3; *sh_r = r - S; }
    S += c3;
    if (S < r && S + c2 >= r) { *sh_bin = base + 2; *sh_r = r - S; }
    S += c2;
    if (S < r && S + c1 >= r) { *sh_bin = base + 1; *sh_r = r - S; }
    S += c1;
    if (S < r && S + c0 >= r) { *sh_bin = base + 0; *sh_r = r - S; }
    __syncthreads();
}

// ---------------- K1: per-row sumsq + class-token dot -> u32 ranking key ----------------
__global__ __launch_bounds__(256) void k_scores(const float* __restrict__ nf,
                                                const float* __restrict__ ct,
                                                unsigned* __restrict__ keys,
                                                float* __restrict__ invn) {
    int wave = threadIdx.x >> 6;
    int lane = threadIdx.x & 63;
    int row  = blockIdx.x * 4 + wave;
    const float* x = nf + (size_t)row * CC;
    float4 a  = ((const float4*)x)[lane];
    float2 c2 = ((const float2*)(x + 256))[lane];
    float4 ta = ((const float4*)ct)[lane];
    float2 tc = ((const float2*)(ct + 256))[lane];
    float ss = a.x*a.x + a.y*a.y + a.z*a.z + a.w*a.w + c2.x*c2.x + c2.y*c2.y;
    float dt = ta.x*a.x + ta.y*a.y + ta.z*a.z + ta.w*a.w + tc.x*c2.x + tc.y*c2.y;
#pragma unroll
    for (int off = 32; off; off >>= 1) {
        ss += __shfl_xor(ss, off, 64);
        dt += __shfl_xor(dt, off, 64);
    }
    if (lane == 0) {
        float inv = 1.0f / fmaxf(sqrtf(ss), 1e-12f);
        invn[row] = inv;
        keys[row] = fkey(dt * inv);
    }
}

// ---------------- K2: top-128 per batch, single-scan 12-bit radix + fused center gather ----------------
__global__ __launch_bounds__(1024) void k_top128(const unsigned* __restrict__ keys,
                                                 const float* __restrict__ nf,
                                                 const float* __restrict__ invn,
                                                 ushort_t* __restrict__ Ahi,
                                                 ushort_t* __restrict__ Alo,
                                                 float* __restrict__ meta) {
    __shared__ unsigned hist[4096];
    __shared__ int wsum[16];
    __shared__ int sh_bin, sh_r;
    __shared__ unsigned cu[NE];
    __shared__ int cil[NE];
    __shared__ unsigned eqk[CAP];
    __shared__ int eqi[CAP];
    __shared__ int cnt_gt, cnt_eq;
    __shared__ int ocid[NE];
    int b = blockIdx.x;
    int t = threadIdx.x;
    const uint4* rowv = (const uint4*)(keys + b * NN);
    if (t == 0) { cnt_gt = 0; cnt_eq = 0; }
    ((uint4*)hist)[t] = make_uint4(0, 0, 0, 0);
    __syncthreads();
    uint4 u0 = rowv[t], u1 = rowv[t + 1024], u2 = rowv[t + 2048], u3 = rowv[t + 3072];
    atomicAdd(&hist[u0.x >> 20], 1u); atomicAdd(&hist[u0.y >> 20], 1u);
    atomicAdd(&hist[u0.z >> 20], 1u); atomicAdd(&hist[u0.w >> 20], 1u);
    atomicAdd(&hist[u1.x >> 20], 1u); atomicAdd(&hist[u1.y >> 20], 1u);
    atomicAdd(&hist[u1.z >> 20], 1u); atomicAdd(&hist[u1.w >> 20], 1u);
    atomicAdd(&hist[u2.x >> 20], 1u); atomicAdd(&hist[u2.y >> 20], 1u);
    atomicAdd(&hist[u2.z >> 20], 1u); atomicAdd(&hist[u2.w >> 20], 1u);
    atomicAdd(&hist[u3.x >> 20], 1u); atomicAdd(&hist[u3.y >> 20], 1u);
    atomicAdd(&hist[u3.z >> 20], 1u); atomicAdd(&hist[u3.w >> 20], 1u);
    __syncthreads();
    bin_select4k(hist, t, wsum, &sh_bin, &sh_r, NE);
    unsigned bin = (unsigned)sh_bin;
    int r = sh_r;
#define EMIT128(uu, nn) { unsigned tb = (uu) >> 20; \
    if (tb > bin) { int p = atomicAdd(&cnt_gt, 1); cu[p] = (uu); cil[p] = (nn); } \
    else if (tb == bin) { int p = atomicAdd(&cnt_eq, 1); if (p < CAP) { eqk[p] = (uu); eqi[p] = (nn); } } }
    EMIT128(u0.x, 4*t+0); EMIT128(u0.y, 4*t+1); EMIT128(u0.z, 4*t+2); EMIT128(u0.w, 4*t+3);
    EMIT128(u1.x, 4096+4*t+0); EMIT128(u1.y, 4096+4*t+1); EMIT128(u1.z, 4096+4*t+2); EMIT128(u1.w, 4096+4*t+3);
    EMIT128(u2.x, 8192+4*t+0); EMIT128(u2.y, 8192+4*t+1); EMIT128(u2.z, 8192+4*t+2); EMIT128(u2.w, 8192+4*t+3);
    EMIT128(u3.x, 12288+4*t+0); EMIT128(u3.y, 12288+4*t+1); EMIT128(u3.z, 12288+4*t+2); EMIT128(u3.w, 12288+4*t+3);
#undef EMIT128
    __syncthreads();
    int ne = cnt_eq < CAP ? cnt_eq : CAP;
    for (int i = t; i < ne; i += 1024) {
        unsigned ki = eqk[i]; int ii = eqi[i], rk = 0;
        for (int j = 0; j < ne; ++j) {
            unsigned kj = eqk[j];
            rk += (kj > ki) || (kj == ki && eqi[j] < ii);
        }
        if (rk < r) { cu[cnt_gt + rk] = ki; cil[cnt_gt + rk] = ii; }
    }
    __syncthreads();
    if (t < NE) {
        unsigned mu = cu[t]; int mi = cil[t], rk = 0;
#pragma unroll 4
        for (int j = 0; j < NE; ++j) {
            unsigned ou = cu[j]; int oi = cil[j];
            rk += (ou > mu) || (ou == mu && oi < mi);
        }
        ocid[rk] = mi;
    }
    __syncthreads();
    // ---- fused: gather centers, l2-normalize, exact-RNE bf16 hi/lo split ----
    {
        int e = t >> 3, part = t & 7;       // 128 edges x 8 threads
        int ci = ocid[e];
        float inv = invn[b * NN + ci];
        const float4* src = (const float4*)(nf + ((size_t)b * NN + ci) * CC) + part * 12;
        ushort_t* dh = Ahi + ((size_t)b * NE + e) * CC + part * 48;
        ushort_t* dl = Alo + ((size_t)b * NE + e) * CC + part * 48;
#pragma unroll
        for (int i = 0; i < 12; ++i) {
            float4 f = src[i];
            f.x *= inv; f.y *= inv; f.z *= inv; f.w *= inv;
            ushort4 h, l;
            h.x = bf16rne(f.x); l.x = bf16rne(f.x - bf16tof(h.x));
            h.y = bf16rne(f.y); l.y = bf16rne(f.y - bf16tof(h.y));
            h.z = bf16rne(f.z); l.z = bf16rne(f.z - bf16tof(h.z));
            h.w = bf16rne(f.w); l.w = bf16rne(f.w - bf16tof(h.w));
            ((ushort4*)dh)[i] = h;
            ((ushort4*)dl)[i] = l;
        }
    }
    if (t < NE) {
        int ci = ocid[t];
        float zc = (float)(ci >> 10) * 2.0f;
        float yc = (float)((ci >> 5) & 31);
        float xc = (float)(ci & 31);
        float mz = fmaxf(zc * zc, (30.f - zc) * (30.f - zc));
        float my = fmaxf(yc * yc, (31.f - yc) * (31.f - yc));
        float mx = fmaxf(xc * xc, (31.f - xc) * (31.f - xc));
        float md = sqrtf(mz + my + mx);
        int be = b * NE + t;
        meta[be * 4 + 0] = zc;
        meta[be * 4 + 1] = yc;
        meta[be * 4 + 2] = xc;
        meta[be * 4 + 3] = 1.0f / (md + 1e-8f);
    }
}

// ---------------- K3: bf16-split MFMA GEMM, 64 edges x 128 nodes/block ----------------
// acc = Ahi*Bhi + Ahi*Blo + Alo*Bhi (fp32 accum). 1024 blocks = 4 blocks/CU.
// Full 512B-per-e-row writes per block (no partial-line write amplification).
__global__ __launch_bounds__(256, 4) void k_gemm(const float* __restrict__ nf,
                                                 const ushort_t* __restrict__ Ahi,
                                                 const ushort_t* __restrict__ Alo,
                                                 const float* __restrict__ invn,
                                                 const float* __restrict__ meta,
                                                 const float* __restrict__ temp,
                                                 unsigned* __restrict__ outk) {
    __shared__ ushort_t Ah[4][66][8], Al[4][66][8];     // [k8][e 64+pad][8]
    __shared__ ushort_t Bh[4][130][8], Bl[4][130][8];   // [k8][n 128+pad][8]
    __shared__ float ms[64 * 4];
    __shared__ float invs_s[128];
    int b  = blockIdx.y;
    int e0 = (blockIdx.x & 1) * 64;          // which 64-edge half
    int n0 = (blockIdx.x >> 1) * 128;        // which 128-node tile
    int t  = threadIdx.x;
    int w = t >> 6, lane = t & 63, quad = lane >> 4, mrow = lane & 15;
    int m0 = (w & 1) * 32, nw0 = (w >> 1) * 64;
    for (int i = t; i < 64 * 4; i += 256) ms[i] = meta[(b * NE + e0) * 4 + i];
    if (t < 128) invs_s[t] = invn[b * NN + n0 + t];
    f32x4 acc[2][4];
#pragma unroll
    for (int i = 0; i < 2; ++i)
#pragma unroll
        for (int j = 0; j < 4; ++j) acc[i][j] = (f32x4)0.f;
    const ushort_t* Abh = Ahi + ((size_t)b * NE + e0) * CC;
    const ushort_t* Abl = Alo + ((size_t)b * NE + e0) * CC;
    const float* Bb = nf + ((size_t)b * NN + n0) * CC;
    // staging addresses: A: 64e x 4 k8-chunks = 256 (1/thread); B: 128n x 4 = 512 (2/thread)
    int ae = t >> 2, ak8 = t & 3;
    const ushort_t* agh = Abh + (size_t)ae * CC + ak8 * 8;
    const ushort_t* agl = Abl + (size_t)ae * CC + ak8 * 8;
    int bn0 = t >> 2, bk80 = t & 3;
    int bn1 = (t + 256) >> 2, bk81 = (t + 256) & 3;
    const float* bs0 = Bb + (size_t)bn0 * CC + bk80 * 8;
    const float* bs1 = Bb + (size_t)bn1 * CC + bk81 * 8;
    uint4 pAh, pAl;
    float4 pB0a, pB0b, pB1a, pB1b;
    pAh = *(const uint4*)agh;
    pAl = *(const uint4*)agl;
    pB0a = ((const float4*)bs0)[0]; pB0b = ((const float4*)bs0)[1];
    pB1a = ((const float4*)bs1)[0]; pB1b = ((const float4*)bs1)[1];
    for (int kt = 0; kt < CC; kt += 32) {
        __syncthreads();
        *(uint4*)&Ah[ak8][ae][0] = pAh;
        *(uint4*)&Al[ak8][ae][0] = pAl;
        {
            uint4 ph, pl;
            cvt2(pB0a.x, pB0a.y, ph.x, pl.x);
            cvt2(pB0a.z, pB0a.w, ph.y, pl.y);
            cvt2(pB0b.x, pB0b.y, ph.z, pl.z);
            cvt2(pB0b.z, pB0b.w, ph.w, pl.w);
            *(uint4*)&Bh[bk80][bn0][0] = ph;
            *(uint4*)&Bl[bk80][bn0][0] = pl;
            cvt2(pB1a.x, pB1a.y, ph.x, pl.x);
            cvt2(pB1a.z, pB1a.w, ph.y, pl.y);
            cvt2(pB1b.x, pB1b.y, ph.z, pl.z);
            cvt2(pB1b.z, pB1b.w, ph.w, pl.w);
            *(uint4*)&Bh[bk81][bn1][0] = ph;
            *(uint4*)&Bl[bk81][bn1][0] = pl;
        }
        if (kt + 32 < CC) {                  // register prefetch of next K-chunk
            pAh = *(const uint4*)(agh + kt + 32);
            pAl = *(const uint4*)(agl + kt + 32);
            pB0a = ((const float4*)(bs0 + kt + 32))[0]; pB0b = ((const float4*)(bs0 + kt + 32))[1];
            pB1a = ((const float4*)(bs1 + kt + 32))[0]; pB1b = ((const float4*)(bs1 + kt + 32))[1];
        }
        __syncthreads();
        bf16x8 afh[2], afl[2], bfh[4], bfl[4];
#pragma unroll
        for (int i = 0; i < 2; ++i) {
            int m = m0 + i * 16 + mrow;
            afh[i] = *(const bf16x8*)&Ah[quad][m][0];
            afl[i] = *(const bf16x8*)&Al[quad][m][0];
        }
#pragma unroll
        for (int j = 0; j < 4; ++j) {
            int n = nw0 + j * 16 + mrow;
            bfh[j] = *(const bf16x8*)&Bh[quad][n][0];
            bfl[j] = *(const bf16x8*)&Bl[quad][n][0];
        }
#pragma unroll
        for (int i = 0; i < 2; ++i)
#pragma unroll
            for (int j = 0; j < 4; ++j) {
                acc[i][j] = MFMA(afh[i], bfh[j], acc[i][j]);
                acc[i][j] = MFMA(afh[i], bfl[j], acc[i][j]);
                acc[i][j] = MFMA(afl[i], bfh[j], acc[i][j]);
            }
    }
    float scale = 0.9f / temp[0];
#pragma unroll
    for (int j = 0; j < 4; ++j) {
        int nloc = nw0 + j * 16 + mrow;
        int n = n0 + nloc;
        float invnn = invs_s[nloc];
        float zf = (float)(n >> 10) * 2.0f;
        float yf = (float)((n >> 5) & 31);
        float xf = (float)(n & 31);
#pragma unroll
        for (int i = 0; i < 2; ++i) {
#pragma unroll
            for (int r = 0; r < 4; ++r) {
                int el = m0 + i * 16 + quad * 4 + r;
                float zc = ms[el * 4 + 0], yc = ms[el * 4 + 1], xc = ms[el * 4 + 2], ivd = ms[el * 4 + 3];
                float dz = zf - zc, dy = yf - yc, dx = xf - xc;
                float dist = sqrtf(dz * dz + dy * dy + dx * dx);
                float v = scale * invnn * acc[i][j][r] + 0.1f * (1.0f - dist * ivd);
                outk[((size_t)(b * NE + e0 + el)) * NN + n] = fkey(v);
            }
        }
    }
}

// ---------------- K4: top-64 per hyperedge, single-scan 12-bit radix (set only) ----------------
__global__ __launch_bounds__(1024) void k_top64(const unsigned* __restrict__ comb,
                                                int* __restrict__ sel) {
    __shared__ unsigned hist[4096];
    __shared__ int wsum[16];
    __shared__ int sh_bin, sh_r;
    __shared__ unsigned eqk[CAP];
    __shared__ int eqi[CAP];
    __shared__ int cnt_gt, cnt_eq;
    int be = blockIdx.x;
    int t  = threadIdx.x;
    const uint4* rowv = (const uint4*)(comb + (size_t)be * NN);
    if (t == 0) { cnt_gt = 0; cnt_eq = 0; }
    ((uint4*)hist)[t] = make_uint4(0, 0, 0, 0);
    __syncthreads();
    uint4 u0 = rowv[t], u1 = rowv[t + 1024], u2 = rowv[t + 2048], u3 = rowv[t + 3072];
    atomicAdd(&hist[u0.x >> 20], 1u); atomicAdd(&hist[u0.y >> 20], 1u);
    atomicAdd(&hist[u0.z >> 20], 1u); atomicAdd(&hist[u0.w >> 20], 1u);
    atomicAdd(&hist[u1.x >> 20], 1u); atomicAdd(&hist[u1.y >> 20], 1u);
    atomicAdd(&hist[u1.z >> 20], 1u); atomicAdd(&hist[u1.w >> 20], 1u);
    atomicAdd(&hist[u2.x >> 20], 1u); atomicAdd(&hist[u2.y >> 20], 1u);
    atomicAdd(&hist[u2.z >> 20], 1u); atomicAdd(&hist[u2.w >> 20], 1u);
    atomicAdd(&hist[u3.x >> 20], 1u); atomicAdd(&hist[u3.y >> 20], 1u);
    atomicAdd(&hist[u3.z >> 20], 1u); atomicAdd(&hist[u3.w >> 20], 1u);
    __syncthreads();
    bin_select4k(hist, t, wsum, &sh_bin, &sh_r, KK);
    unsigned bin = (unsigned)sh_bin;
    int r = sh_r;
#define EMIT64(uu, nn) { unsigned tb = (uu) >> 20; \
    if (tb > bin) { int p = atomicAdd(&cnt_gt, 1); sel[be * KK + p] = (nn); } \
    else if (tb == bin) { int p = atomicAdd(&cnt_eq, 1); if (p < CAP) { eqk[p] = (uu); eqi[p] = (nn); } } }
    EMIT64(u0.x, 4*t+0); EMIT64(u0.y, 4*t+1); EMIT64(u0.z, 4*t+2); EMIT64(u0.w, 4*t+3);
    EMIT64(u1.x, 4096+4*t+0); EMIT64(u1.y, 4096+4*t+1); EMIT64(u1.z, 4096+4*t+2); EMIT64(u1.w, 4096+4*t+3);
    EMIT64(u2.x, 8192+4*t+0); EMIT64(u2.y, 8192+4*t+1); EMIT64(u2.z, 8192+4*t+2); EMIT64(u2.w, 8192+4*t+3);
    EMIT64(u3.x, 12288+4*t+0); EMIT64(u3.y, 12288+4*t+1); EMIT64(u3.z, 12288+4*t+2); EMIT64(u3.w, 12288+4*t+3);
#undef EMIT64
    __syncthreads();
    int ne = cnt_eq < CAP ? cnt_eq : CAP;
    for (int i = t; i < ne; i += 1024) {
        unsigned ki = eqk[i]; int ii = eqi[i], rk = 0;
        for (int j = 0; j < ne; ++j) {
            unsigned kj = eqk[j];
            rk += (kj > ki) || (kj == ki && eqi[j] < ii);
        }
        if (rk < r) sel[be * KK + cnt_gt + rk] = ii;
    }
}

// ---------------- K5: scatter ones into H (B, N, Ne) ----------------
__global__ __launch_bounds__(256) void k_scatter(const int* __restrict__ sel,
                                                 float* __restrict__ H) {
    int gid = blockIdx.x * 256 + threadIdx.x;
    int b = gid >> 13;
    int e = (gid >> 6) & 127;
    int n = sel[gid];
    H[((size_t)b * NN + n) * NE + e] = 1.0f;
}

extern "C" void kernel_launch(void* const* d_in, const int* in_sizes, int n_in,
                              void* d_out, int out_size, void* d_ws, size_t ws_size,
                              hipStream_t stream) {
    const float* nf   = (const float*)d_in[0];
    const float* ct   = (const float*)d_in[1];
    const float* temp = (const float*)d_in[2];
    float* out = (float*)d_out;                  // (B,N,Ne) f32 — also (B,Ne,N) u32-key scratch

    unsigned* keys = (unsigned*)d_ws;                      // B*N u32
    float* invn    = (float*)(keys + BB * NN);             // B*N f32
    float* meta    = invn + BB * NN;                       // B*NE*4 f32
    ushort_t* Ahi  = (ushort_t*)(meta + BB * NE * 4);      // B*NE*C bf16
    ushort_t* Alo  = Ahi + (size_t)BB * NE * CC;           // B*NE*C bf16
    int* sel       = (int*)(Alo + (size_t)BB * NE * CC);   // B*NE*KK

    k_scores <<<BB * NN / 4, 256, 0, stream>>>(nf, ct, keys, invn);
    k_top128 <<<BB, 1024, 0, stream>>>(keys, nf, invn, Ahi, Alo, meta);
    k_gemm   <<<dim3(NN / 128 * 2, BB), 256, 0, stream>>>(nf, Ahi, Alo, invn, meta, temp, (unsigned*)out);
    k_top64  <<<BB * NE, 1024, 0, stream>>>((const unsigned*)out, sel);
    hipMemsetAsync(d_out, 0, (size_t)BB * NN * NE * sizeof(float), stream);
    k_scatter<<<BB * NE * KK / 256, 256, 0, stream>>>(sel, out);
}

// Round 6
// 236.468 us; speedup vs baseline: 1.2144x; 1.0759x over previous
//
#include <hip/hip_runtime.h>
#include <math.h>

#define BB 4
#define NN 16384
#define CC 384
#define NE 128
#define KK 64
#define CAP 1024

typedef unsigned short ushort_t;
typedef __attribute__((ext_vector_type(8))) short bf16x8;
typedef __attribute__((ext_vector_type(4))) float f32x4;
#define MFMA(a, b, c) __builtin_amdgcn_mfma_f32_16x16x32_bf16(a, b, c, 0, 0, 0)

// Monotone map: larger float -> larger u32
__device__ inline unsigned fkey(float f) {
    unsigned b = __float_as_uint(f);
    return (b & 0x80000000u) ? ~b : (b | 0x80000000u);
}
__device__ inline ushort_t bf16rne(float f) {
    unsigned u = __float_as_uint(f);
    unsigned r = u + 0x7FFFu + ((u >> 16) & 1u);
    return (ushort_t)(r >> 16);
}
__device__ inline float bf16tof(ushort_t h) {
    return __uint_as_float(((unsigned)h) << 16);
}
// Cheap near-RNE hi/lo split for a pair of floats (unbiased residual ~2^-17)
__device__ inline void cvt2(float fa, float fb, unsigned& hp, unsigned& lp) {
    unsigned ua = __float_as_uint(fa), ub = __float_as_uint(fb);
    unsigned ra = ua + 0x8000u, rb = ub + 0x8000u;
    hp = (ra >> 16) | (rb & 0xFFFF0000u);
    float ha = __uint_as_float(ra & 0xFFFF0000u);
    float hb = __uint_as_float(rb & 0xFFFF0000u);
    float la = fa - ha, lb = fb - hb;           // exact (Sterbenz)
    unsigned lra = __float_as_uint(la) + 0x8000u;
    unsigned lrb = __float_as_uint(lb) + 0x8000u;
    lp = (lra >> 16) | (lrb & 0xFFFF0000u);
}

// Parallel bin select over 4096-bin LDS histogram (1024 threads, 16 waves).
__device__ inline void bin_select4k(const unsigned* hist, int t, int* wsum,
                                    int* sh_bin, int* sh_r, int r) {
    int base = t * 4;
    int c0 = hist[base], c1 = hist[base + 1], c2 = hist[base + 2], c3 = hist[base + 3];
    int csum = c0 + c1 + c2 + c3;
    int lane = t & 63, wid = t >> 6;
    int x = csum;
#pragma unroll
    for (int off = 1; off < 64; off <<= 1) {
        int v = __shfl_down(x, off, 64);
        if (lane + off < 64) x += v;     // inclusive suffix within wave
    }
    if (lane == 0) wsum[wid] = x;
    __syncthreads();
    int after = 0;
    for (int w2 = wid + 1; w2 < 16; ++w2) after += wsum[w2];
    int S = x - csum + after;            // elems in bins strictly above base+3
    if (S < r && S + c3 >= r) { *sh_bin = base + 3; *sh_r = r - S; }
    S += c3;
    if (S < r && S + c2 >= r) { *sh_bin = base + 2; *sh_r = r - S; }
    S += c2;
    if (S < r && S + c1 >= r) { *sh_bin = base + 1; *sh_r = r - S; }
    S += c1;
    if (S < r && S + c0 >= r) { *sh_bin = base + 0; *sh_r = r - S; }
    __syncthreads();
}

// ---------------- K1: per-row sumsq + class-token dot -> u32 ranking key ----------------
__global__ __launch_bounds__(256) void k_scores(const float* __restrict__ nf,
                                                const float* __restrict__ ct,
                                                unsigned* __restrict__ keys,
                                                float* __restrict__ invn) {
    int wave = threadIdx.x >> 6;
    int lane = threadIdx.x & 63;
    int row  = blockIdx.x * 4 + wave;
    const float* x = nf + (size_t)row * CC;
    float4 a  = ((const float4*)x)[lane];
    float2 c2 = ((const float2*)(x + 256))[lane];
    float4 ta = ((const float4*)ct)[lane];
    float2 tc = ((const float2*)(ct + 256))[lane];
    float ss = a.x*a.x + a.y*a.y + a.z*a.z + a.w*a.w + c2.x*c2.x + c2.y*c2.y;
    float dt = ta.x*a.x + ta.y*a.y + ta.z*a.z + ta.w*a.w + tc.x*c2.x + tc.y*c2.y;
#pragma unroll
    for (int off = 32; off; off >>= 1) {
        ss += __shfl_xor(ss, off, 64);
        dt += __shfl_xor(dt, off, 64);
    }
    if (lane == 0) {
        float inv = 1.0f / fmaxf(sqrtf(ss), 1e-12f);
        invn[row] = inv;
        keys[row] = fkey(dt * inv);
    }
}

// ---------------- K2: top-128 per batch, single-scan 12-bit radix ----------------
__global__ __launch_bounds__(1024) void k_top128(const unsigned* __restrict__ keys,
                                                 int* __restrict__ cidx,
                                                 float* __restrict__ meta) {
    __shared__ unsigned hist[4096];
    __shared__ int wsum[16];
    __shared__ int sh_bin, sh_r;
    __shared__ unsigned cu[NE];
    __shared__ int cil[NE];
    __shared__ unsigned eqk[CAP];
    __shared__ int eqi[CAP];
    __shared__ int cnt_gt, cnt_eq;
    __shared__ int ocid[NE];
    int b = blockIdx.x;
    int t = threadIdx.x;
    const uint4* rowv = (const uint4*)(keys + b * NN);
    if (t == 0) { cnt_gt = 0; cnt_eq = 0; }
    ((uint4*)hist)[t] = make_uint4(0, 0, 0, 0);
    __syncthreads();
    uint4 u0 = rowv[t], u1 = rowv[t + 1024], u2 = rowv[t + 2048], u3 = rowv[t + 3072];
    atomicAdd(&hist[u0.x >> 20], 1u); atomicAdd(&hist[u0.y >> 20], 1u);
    atomicAdd(&hist[u0.z >> 20], 1u); atomicAdd(&hist[u0.w >> 20], 1u);
    atomicAdd(&hist[u1.x >> 20], 1u); atomicAdd(&hist[u1.y >> 20], 1u);
    atomicAdd(&hist[u1.z >> 20], 1u); atomicAdd(&hist[u1.w >> 20], 1u);
    atomicAdd(&hist[u2.x >> 20], 1u); atomicAdd(&hist[u2.y >> 20], 1u);
    atomicAdd(&hist[u2.z >> 20], 1u); atomicAdd(&hist[u2.w >> 20], 1u);
    atomicAdd(&hist[u3.x >> 20], 1u); atomicAdd(&hist[u3.y >> 20], 1u);
    atomicAdd(&hist[u3.z >> 20], 1u); atomicAdd(&hist[u3.w >> 20], 1u);
    __syncthreads();
    bin_select4k(hist, t, wsum, &sh_bin, &sh_r, NE);
    unsigned bin = (unsigned)sh_bin;
    int r = sh_r;
#define EMIT128(uu, nn) { unsigned tb = (uu) >> 20; \
    if (tb > bin) { int p = atomicAdd(&cnt_gt, 1); cu[p] = (uu); cil[p] = (nn); } \
    else if (tb == bin) { int p = atomicAdd(&cnt_eq, 1); if (p < CAP) { eqk[p] = (uu); eqi[p] = (nn); } } }
    EMIT128(u0.x, 4*t+0); EMIT128(u0.y, 4*t+1); EMIT128(u0.z, 4*t+2); EMIT128(u0.w, 4*t+3);
    EMIT128(u1.x, 4096+4*t+0); EMIT128(u1.y, 4096+4*t+1); EMIT128(u1.z, 4096+4*t+2); EMIT128(u1.w, 4096+4*t+3);
    EMIT128(u2.x, 8192+4*t+0); EMIT128(u2.y, 8192+4*t+1); EMIT128(u2.z, 8192+4*t+2); EMIT128(u2.w, 8192+4*t+3);
    EMIT128(u3.x, 12288+4*t+0); EMIT128(u3.y, 12288+4*t+1); EMIT128(u3.z, 12288+4*t+2); EMIT128(u3.w, 12288+4*t+3);
#undef EMIT128
    __syncthreads();
    int ne = cnt_eq < CAP ? cnt_eq : CAP;
    for (int i = t; i < ne; i += 1024) {
        unsigned ki = eqk[i]; int ii = eqi[i], rk = 0;
        for (int j = 0; j < ne; ++j) {
            unsigned kj = eqk[j];
            rk += (kj > ki) || (kj == ki && eqi[j] < ii);
        }
        if (rk < r) { cu[cnt_gt + rk] = ki; cil[cnt_gt + rk] = ii; }
    }
    __syncthreads();
    if (t < NE) {
        unsigned mu = cu[t]; int mi = cil[t], rk = 0;
#pragma unroll 4
        for (int j = 0; j < NE; ++j) {
            unsigned ou = cu[j]; int oi = cil[j];
            rk += (ou > mu) || (ou == mu && oi < mi);
        }
        ocid[rk] = mi;
        cidx[b * NE + rk] = mi;
    }
    __syncthreads();
    if (t < NE) {
        int ci = ocid[t];
        float zc = (float)(ci >> 10) * 2.0f;
        float yc = (float)((ci >> 5) & 31);
        float xc = (float)(ci & 31);
        float mz = fmaxf(zc * zc, (30.f - zc) * (30.f - zc));
        float my = fmaxf(yc * yc, (31.f - yc) * (31.f - yc));
        float mx = fmaxf(xc * xc, (31.f - xc) * (31.f - xc));
        float md = sqrtf(mz + my + mx);
        int be = b * NE + t;
        meta[be * 4 + 0] = zc;
        meta[be * 4 + 1] = yc;
        meta[be * 4 + 2] = xc;
        meta[be * 4 + 3] = 1.0f / (md + 1e-8f);
    }
}

// ---------------- K2b: gather centers -> exact-RNE bf16 hi/lo split ----------------
__global__ __launch_bounds__(64) void k_centers(const float* __restrict__ nf,
                                                const float* __restrict__ invn,
                                                const int* __restrict__ cidx,
                                                ushort_t* __restrict__ Ahi,
                                                ushort_t* __restrict__ Alo) {
    int be = blockIdx.x;
    int b  = be >> 7;
    int l  = threadIdx.x;
    int ci = cidx[be];
    float inv = invn[b * NN + ci];
    const float* src = nf + ((size_t)b * NN + ci) * CC;
    float4 a  = ((const float4*)src)[l];
    float2 c2 = ((const float2*)(src + 256))[l];
    a.x *= inv; a.y *= inv; a.z *= inv; a.w *= inv;
    c2.x *= inv; c2.y *= inv;
    ushort4 h4; ushort2 h2;
    h4.x = bf16rne(a.x); h4.y = bf16rne(a.y); h4.z = bf16rne(a.z); h4.w = bf16rne(a.w);
    h2.x = bf16rne(c2.x); h2.y = bf16rne(c2.y);
    ushort4 l4; ushort2 l2;
    l4.x = bf16rne(a.x - bf16tof(h4.x)); l4.y = bf16rne(a.y - bf16tof(h4.y));
    l4.z = bf16rne(a.z - bf16tof(h4.z)); l4.w = bf16rne(a.w - bf16tof(h4.w));
    l2.x = bf16rne(c2.x - bf16tof(h2.x)); l2.y = bf16rne(c2.y - bf16tof(h2.y));
    ushort_t* dh = Ahi + (size_t)be * CC;
    ushort_t* dl = Alo + (size_t)be * CC;
    ((ushort4*)dh)[l] = h4;
    ((ushort2*)(dh + 256))[l] = h2;
    ((ushort4*)dl)[l] = l4;
    ((ushort2*)(dl + 256))[l] = l2;
}

// ---------------- K3: bf16-split MFMA GEMM, 64 edges x 128 nodes/block ----------------
// acc = Ahi*Bhi + Ahi*Blo + Alo*Bhi (fp32 accum). 1024 blocks = 4 blocks/CU.
// Block swizzle pairs the two e-halves of one n-tile onto the same XCD (id mod 8).
__global__ __launch_bounds__(256, 4) void k_gemm(const float* __restrict__ nf,
                                                 const ushort_t* __restrict__ Ahi,
                                                 const ushort_t* __restrict__ Alo,
                                                 const float* __restrict__ invn,
                                                 const float* __restrict__ meta,
                                                 const float* __restrict__ temp,
                                                 unsigned* __restrict__ outk) {
    __shared__ ushort_t Ah[4][66][8], Al[4][66][8];     // [k8][e 64+pad][8]
    __shared__ ushort_t Bh[4][130][8], Bl[4][130][8];   // [k8][n 128+pad][8]
    __shared__ float ms[64 * 4];
    __shared__ float invs_s[128];
    int b  = blockIdx.y;
    int x  = blockIdx.x;
    int low = x & 15;
    int e0 = (low >> 3) * 64;                    // e-half; pair-mates are ≡ mod 8
    int nt = (x >> 4) * 8 + (low & 7);
    int n0 = nt * 128;
    int t  = threadIdx.x;
    int w = t >> 6, lane = t & 63, quad = lane >> 4, mrow = lane & 15;
    int m0 = (w & 1) * 32, nw0 = (w >> 1) * 64;
    for (int i = t; i < 64 * 4; i += 256) ms[i] = meta[(b * NE + e0) * 4 + i];
    if (t < 128) invs_s[t] = invn[b * NN + n0 + t];
    f32x4 acc[2][4];
#pragma unroll
    for (int i = 0; i < 2; ++i)
#pragma unroll
        for (int j = 0; j < 4; ++j) acc[i][j] = (f32x4)0.f;
    const ushort_t* Abh = Ahi + ((size_t)b * NE + e0) * CC;
    const ushort_t* Abl = Alo + ((size_t)b * NE + e0) * CC;
    const float* Bb = nf + ((size_t)b * NN + n0) * CC;
    int ae = t >> 2, ak8 = t & 3;
    const ushort_t* agh = Abh + (size_t)ae * CC + ak8 * 8;
    const ushort_t* agl = Abl + (size_t)ae * CC + ak8 * 8;
    int bn0 = t >> 2, bk80 = t & 3;
    int bn1 = (t + 256) >> 2, bk81 = (t + 256) & 3;
    const float* bs0 = Bb + (size_t)bn0 * CC + bk80 * 8;
    const float* bs1 = Bb + (size_t)bn1 * CC + bk81 * 8;
    uint4 pAh, pAl;
    float4 pB0a, pB0b, pB1a, pB1b;
    pAh = *(const uint4*)agh;
    pAl = *(const uint4*)agl;
    pB0a = ((const float4*)bs0)[0]; pB0b = ((const float4*)bs0)[1];
    pB1a = ((const float4*)bs1)[0]; pB1b = ((const float4*)bs1)[1];
    for (int kt = 0; kt < CC; kt += 32) {
        __syncthreads();
        *(uint4*)&Ah[ak8][ae][0] = pAh;
        *(uint4*)&Al[ak8][ae][0] = pAl;
        {
            uint4 ph, pl;
            cvt2(pB0a.x, pB0a.y, ph.x, pl.x);
            cvt2(pB0a.z, pB0a.w, ph.y, pl.y);
            cvt2(pB0b.x, pB0b.y, ph.z, pl.z);
            cvt2(pB0b.z, pB0b.w, ph.w, pl.w);
            *(uint4*)&Bh[bk80][bn0][0] = ph;
            *(uint4*)&Bl[bk80][bn0][0] = pl;
            cvt2(pB1a.x, pB1a.y, ph.x, pl.x);
            cvt2(pB1a.z, pB1a.w, ph.y, pl.y);
            cvt2(pB1b.x, pB1b.y, ph.z, pl.z);
            cvt2(pB1b.z, pB1b.w, ph.w, pl.w);
            *(uint4*)&Bh[bk81][bn1][0] = ph;
            *(uint4*)&Bl[bk81][bn1][0] = pl;
        }
        if (kt + 32 < CC) {                  // register prefetch of next K-chunk
            pAh = *(const uint4*)(agh + kt + 32);
            pAl = *(const uint4*)(agl + kt + 32);
            pB0a = ((const float4*)(bs0 + kt + 32))[0]; pB0b = ((const float4*)(bs0 + kt + 32))[1];
            pB1a = ((const float4*)(bs1 + kt + 32))[0]; pB1b = ((const float4*)(bs1 + kt + 32))[1];
        }
        __syncthreads();
        bf16x8 afh[2], afl[2], bfh[4], bfl[4];
#pragma unroll
        for (int i = 0; i < 2; ++i) {
            int m = m0 + i * 16 + mrow;
            afh[i] = *(const bf16x8*)&Ah[quad][m][0];
            afl[i] = *(const bf16x8*)&Al[quad][m][0];
        }
#pragma unroll
        for (int j = 0; j < 4; ++j) {
            int n = nw0 + j * 16 + mrow;
            bfh[j] = *(const bf16x8*)&Bh[quad][n][0];
            bfl[j] = *(const bf16x8*)&Bl[quad][n][0];
        }
#pragma unroll
        for (int i = 0; i < 2; ++i)
#pragma unroll
            for (int j = 0; j < 4; ++j) {
                acc[i][j] = MFMA(afh[i], bfh[j], acc[i][j]);
                acc[i][j] = MFMA(afh[i], bfl[j], acc[i][j]);
                acc[i][j] = MFMA(afl[i], bfh[j], acc[i][j]);
            }
    }
    float scale = 0.9f / temp[0];
#pragma unroll
    for (int j = 0; j < 4; ++j) {
        int nloc = nw0 + j * 16 + mrow;
        int n = n0 + nloc;
        float invnn = invs_s[nloc];
        float zf = (float)(n >> 10) * 2.0f;
        float yf = (float)((n >> 5) & 31);
        float xf = (float)(n & 31);
#pragma unroll
        for (int i = 0; i < 2; ++i) {
#pragma unroll
            for (int r = 0; r < 4; ++r) {
                int el = m0 + i * 16 + quad * 4 + r;
                float zc = ms[el * 4 + 0], yc = ms[el * 4 + 1], xc = ms[el * 4 + 2], ivd = ms[el * 4 + 3];
                float dz = zf - zc, dy = yf - yc, dx = xf - xc;
                float dist = sqrtf(dz * dz + dy * dy + dx * dx);
                float v = scale * invnn * acc[i][j][r] + 0.1f * (1.0f - dist * ivd);
                outk[((size_t)(b * NE + e0 + el)) * NN + n] = fkey(v);
            }
        }
    }
}

// ---------------- K4: top-64 per hyperedge -> 16384-bit incidence bitmap ----------------
__global__ __launch_bounds__(1024) void k_top64(const unsigned* __restrict__ comb,
                                                unsigned* __restrict__ bmg) {
    __shared__ unsigned hist[4096];
    __shared__ unsigned bm[512];
    __shared__ int wsum[16];
    __shared__ int sh_bin, sh_r;
    __shared__ unsigned eqk[CAP];
    __shared__ int eqi[CAP];
    __shared__ int cnt_eq;
    int be = blockIdx.x;
    int t  = threadIdx.x;
    const uint4* rowv = (const uint4*)(comb + (size_t)be * NN);
    if (t == 0) cnt_eq = 0;
    ((uint4*)hist)[t] = make_uint4(0, 0, 0, 0);
    if (t < 128) ((uint4*)bm)[t] = make_uint4(0, 0, 0, 0);
    __syncthreads();
    uint4 u0 = rowv[t], u1 = rowv[t + 1024], u2 = rowv[t + 2048], u3 = rowv[t + 3072];
    atomicAdd(&hist[u0.x >> 20], 1u); atomicAdd(&hist[u0.y >> 20], 1u);
    atomicAdd(&hist[u0.z >> 20], 1u); atomicAdd(&hist[u0.w >> 20], 1u);
    atomicAdd(&hist[u1.x >> 20], 1u); atomicAdd(&hist[u1.y >> 20], 1u);
    atomicAdd(&hist[u1.z >> 20], 1u); atomicAdd(&hist[u1.w >> 20], 1u);
    atomicAdd(&hist[u2.x >> 20], 1u); atomicAdd(&hist[u2.y >> 20], 1u);
    atomicAdd(&hist[u2.z >> 20], 1u); atomicAdd(&hist[u2.w >> 20], 1u);
    atomicAdd(&hist[u3.x >> 20], 1u); atomicAdd(&hist[u3.y >> 20], 1u);
    atomicAdd(&hist[u3.z >> 20], 1u); atomicAdd(&hist[u3.w >> 20], 1u);
    __syncthreads();
    bin_select4k(hist, t, wsum, &sh_bin, &sh_r, KK);
    unsigned bin = (unsigned)sh_bin;
    int r = sh_r;
#define EMIT64(uu, nn) { unsigned tb = (uu) >> 20; \
    if (tb > bin) { atomicOr(&bm[(nn) >> 5], 1u << ((nn) & 31)); } \
    else if (tb == bin) { int p = atomicAdd(&cnt_eq, 1); if (p < CAP) { eqk[p] = (uu); eqi[p] = (nn); } } }
    EMIT64(u0.x, 4*t+0); EMIT64(u0.y, 4*t+1); EMIT64(u0.z, 4*t+2); EMIT64(u0.w, 4*t+3);
    EMIT64(u1.x, 4096+4*t+0); EMIT64(u1.y, 4096+4*t+1); EMIT64(u1.z, 4096+4*t+2); EMIT64(u1.w, 4096+4*t+3);
    EMIT64(u2.x, 8192+4*t+0); EMIT64(u2.y, 8192+4*t+1); EMIT64(u2.z, 8192+4*t+2); EMIT64(u2.w, 8192+4*t+3);
    EMIT64(u3.x, 12288+4*t+0); EMIT64(u3.y, 12288+4*t+1); EMIT64(u3.z, 12288+4*t+2); EMIT64(u3.w, 12288+4*t+3);
#undef EMIT64
    __syncthreads();
    int ne = cnt_eq < CAP ? cnt_eq : CAP;
    for (int i = t; i < ne; i += 1024) {
        unsigned ki = eqk[i]; int ii = eqi[i], rk = 0;
        for (int j = 0; j < ne; ++j) {
            unsigned kj = eqk[j];
            rk += (kj > ki) || (kj == ki && eqi[j] < ii);
        }
        if (rk < r) atomicOr(&bm[ii >> 5], 1u << (ii & 31));
    }
    __syncthreads();
    if (t < 128) ((uint4*)(bmg + (size_t)be * 512))[t] = ((uint4*)bm)[t];
}

// ---------------- K5: expand bitmaps -> H (B, N, Ne), fully coalesced ----------------
__global__ __launch_bounds__(256) void k_expand(const unsigned* __restrict__ bmg,
                                                float* __restrict__ H) {
    __shared__ unsigned wl[256];     // 2 words per edge (covers 64 n)
    int b  = blockIdx.y;
    int n0 = blockIdx.x * 64;
    int t  = threadIdx.x;
    int w0 = n0 >> 5;
    wl[t] = bmg[((size_t)b * NE + (t >> 1)) * 512 + w0 + (t & 1)];
    __syncthreads();
    float4* dst = (float4*)(H + ((size_t)b * NN + n0) * NE);
#pragma unroll
    for (int i = 0; i < 8; ++i) {
        int flat = t + 256 * i;          // [0, 2048): n-local*32 + f4
        int nl = flat >> 5, f4 = flat & 31;
        int wsel = nl >> 5, bit = nl & 31;
        int e = f4 * 4;
        float4 v;
        v.x = (float)((wl[(e + 0) * 2 + wsel] >> bit) & 1u);
        v.y = (float)((wl[(e + 1) * 2 + wsel] >> bit) & 1u);
        v.z = (float)((wl[(e + 2) * 2 + wsel] >> bit) & 1u);
        v.w = (float)((wl[(e + 3) * 2 + wsel] >> bit) & 1u);
        dst[flat] = v;
    }
}

extern "C" void kernel_launch(void* const* d_in, const int* in_sizes, int n_in,
                              void* d_out, int out_size, void* d_ws, size_t ws_size,
                              hipStream_t stream) {
    const float* nf   = (const float*)d_in[0];
    const float* ct   = (const float*)d_in[1];
    const float* temp = (const float*)d_in[2];
    float* out = (float*)d_out;                  // (B,N,Ne) f32 — also (B,Ne,N) u32-key scratch

    unsigned* keys = (unsigned*)d_ws;                      // B*N u32
    float* invn    = (float*)(keys + BB * NN);             // B*N f32
    float* meta    = invn + BB * NN;                       // B*NE*4 f32
    ushort_t* Ahi  = (ushort_t*)(meta + BB * NE * 4);      // B*NE*C bf16
    ushort_t* Alo  = Ahi + (size_t)BB * NE * CC;           // B*NE*C bf16
    int* cidx      = (int*)(Alo + (size_t)BB * NE * CC);   // B*NE
    unsigned* bmg  = (unsigned*)(cidx + BB * NE);          // B*NE*512 u32 bitmap

    k_scores <<<BB * NN / 4, 256, 0, stream>>>(nf, ct, keys, invn);
    k_top128 <<<BB, 1024, 0, stream>>>(keys, cidx, meta);
    k_centers<<<BB * NE, 64, 0, stream>>>(nf, invn, cidx, Ahi, Alo);
    k_gemm   <<<dim3(NN / 128 * 2, BB), 256, 0, stream>>>(nf, Ahi, Alo, invn, meta, temp, (unsigned*)out);
    k_top64  <<<BB * NE, 1024, 0, stream>>>((const unsigned*)out, bmg);
    k_expand <<<dim3(NN / 64, BB), 256, 0, stream>>>(bmg, out);
}